// Round 16
// baseline (106.521 us; speedup 1.0000x reference)
//
#include <hip/hip_runtime.h>
#include <math.h>

#define B 8
#define FCH 32
#define WI 256
#define HI 256
#define NW 32
#define NH 32
#define NBOX 1024
#define K 25
#define S 28
#define DZI 16
#define FEAT_FLAT (FCH*S*S)   /* 25088 */
#define FEAT4 (FEAT_FLAT/4)   /* 6272 */
#define OUT_FLAT (2*S*S)      /* 1568 */
#define SMIN 24.0f
#define SMAX 96.0f
#define BIG_SZ (K*B*WI*HI)    /* 13,107,200 */

#define NCHUNK 49
#define CH4 128               /* float4 groups per chunk */

/* 8-byte vector with declared 4-byte alignment: lets clang emit dwordx2 under
   gfx950 unaligned-access mode; falls back to two dword loads otherwise. */
typedef float f2v __attribute__((ext_vector_type(2), aligned(4)));

/* output offsets (floats), in reference return order */
#define O_LOGIT_MU    0
#define O_LOGIT_FEW   8192
#define O_BIG_MASK    8392
#define O_BIG_MASK_NON (O_BIG_MASK + BIG_SZ)
#define O_BIG_IMG     (O_BIG_MASK_NON + BIG_SZ)
#define O_P_MAP       (O_BIG_IMG + BIG_SZ)
#define O_C_FEW       (O_P_MAP + 8192)
#define O_BX          (O_C_FEW + 200)
#define O_BY          (O_BX + 200)
#define O_BW          (O_BY + 200)
#define O_BH          (O_BW + 200)
#define O_Z_SAMPLE    (O_BH + 200)
#define O_KL_LOGIT    (O_Z_SAMPLE + 3200)
#define O_KL_ZWHERE   (O_KL_LOGIT + 8192)
#define O_KL_ZINST    (O_KL_ZWHERE + 800)

__device__ __forceinline__ float sigmoidf_(float x) { return 1.0f / (1.0f + expf(-x)); }
__device__ __forceinline__ float softplusf_(float x) { return fmaxf(x, 0.0f) + log1pf(expf(-fabsf(x))); }
__device__ __forceinline__ float sig_fast(float x) { return 1.0f / (1.0f + __expf(-x)); }
__device__ __forceinline__ float sp_fast(float x)  { return fmaxf(x, 0.0f) + __logf(1.0f + __expf(-fabsf(x))); }
__device__ __forceinline__ float tanh_fast(float x) { /* x >= 0 */
    float e = __expf(-2.0f * x);
    return (1.0f - e) / (1.0f + e);
}

__device__ __forceinline__ float tap256(const float* img, int x, int y) {
    bool in = ((unsigned)x < 256u) && ((unsigned)y < 256u);
    int xc = min(max(x, 0), 255), yc = min(max(y, 0), 255);
    float v = img[xc * 256 + yc];
    return in ? v : 0.0f;
}

__device__ __forceinline__ float tap28(const float* img, int x, int y) {
    bool in = ((unsigned)x < 28u) && ((unsigned)y < 28u);
    int xc = min(max(x, 0), 27), yc = min(max(y, 0), 27);
    float v = img[xc * 28 + yc];
    return in ? v : 0.0f;
}

/* ------------- kernel T: per-batch top-k + box params + kl_zwhere ------------- */
__global__ void topk_kernel(const float* __restrict__ logit_mu,
                            const float* __restrict__ zmu, const float* __restrict__ zstd,
                            const float* __restrict__ w_zw, const float* __restrict__ b_zw,
                            float* __restrict__ out, float* __restrict__ ws_boxes) {
    int b = blockIdx.x;
    int lane = threadIdx.x;          // 64 lanes, one wave
    const float* lg = logit_mu + b * NBOX;
    float vals[16];
    #pragma unroll
    for (int m = 0; m < 16; ++m) vals[m] = lg[m * 64 + lane];

    unsigned taken = 0;
    int sel_idx = 0;
    for (int ks = 0; ks < K; ++ks) {
        float bv = -INFINITY; int bi = 0x7fffffff;
        #pragma unroll
        for (int m = 0; m < 16; ++m) {
            if (!(taken & (1u << m))) {
                float v = vals[m]; int idx = m * 64 + lane;
                if (v > bv || (v == bv && idx < bi)) { bv = v; bi = idx; }
            }
        }
        #pragma unroll
        for (int sh = 32; sh >= 1; sh >>= 1) {
            float ov = __shfl_xor(bv, sh);
            int   oi = __shfl_xor(bi, sh);
            if (ov > bv || (ov == bv && oi < bi)) { bv = ov; bi = oi; }
        }
        if ((bi & 63) == lane) taken |= (1u << (bi >> 6));
        if (lane == ks) sel_idx = bi;
        if (lane == 0) {
            out[O_LOGIT_FEW + ks * B + b] = bv;
            out[O_C_FEW + ks * B + b] = sigmoidf_(bv);
        }
    }

    if (lane < K) {
        int idx = sel_idx;
        int w = idx >> 5, h = idx & 31;
        float mu_c[4];
        #pragma unroll
        for (int c = 0; c < 4; ++c) mu_c[c] = zmu[((b * 4 + c) * NW + w) * NH + h];
        float t[4];
        #pragma unroll
        for (int o = 0; o < 4; ++o) {
            float a = b_zw[o];
            #pragma unroll
            for (int c = 0; c < 4; ++c) a = fmaf(mu_c[c], w_zw[o * 4 + c], a);
            t[o] = sigmoidf_(a);
        }
        float bx = (float)WI * ((float)w + t[0]) / (float)NW;
        float by = (float)HI * ((float)h + t[1]) / (float)NH;
        float bw = SMIN + (SMAX - SMIN) * t[2];
        float bh = SMIN + (SMAX - SMIN) * t[3];
        int kb = lane * B + b;
        out[O_BX + kb] = bx;
        out[O_BY + kb] = by;
        out[O_BW + kb] = bw;
        out[O_BH + kb] = bh;
        ((float4*)ws_boxes)[kb] = make_float4(bx, by, bw, bh);
        #pragma unroll
        for (int c = 0; c < 4; ++c) {
            float m = mu_c[c];
            float sd = zstd[((b * 4 + c) * NW + w) * NH + h];
            out[O_KL_ZWHERE + kb * 4 + c] = 0.5f * (sd * sd + m * m - 1.0f) - logf(sd);
        }
    }
}

/* ------------- kernel W: row-pair crop writer, paired 8B taps -------------
   grid = (32 channels, 200 boxes); block 256 (4 waves).
   Taps (a00,a01) and (a10,a11) are y-adjacent pairs -> one 8-byte load each
   (halves the per-lane TA address count). Boundary-y lanes take the scalar
   fallback; x-mask applied multiplicatively with clamped row index. */
__global__ __launch_bounds__(256) void crop_writer_kernel(
        const float* __restrict__ features, const float* __restrict__ ws_boxes,
        float* __restrict__ crop) {
    int c  = blockIdx.x;            // channel
    int kb = blockIdx.y;            // box (k*8+b)
    int b  = kb & 7;
    float4 box = ((const float4*)ws_boxes)[kb];
    float x_lo = box.x - 0.5f * box.z, y_lo = box.y - 0.5f * box.w;
    float swx = box.z * (1.0f / 27.0f), swy = box.w * (1.0f / 27.0f);
    const float* img = features + ((size_t)b * FCH + c) * (WI * HI);
    float* dst = crop + (size_t)kb * FEAT_FLAT + c * 784;

    int wave = threadIdx.x >> 6, lane = threadIdx.x & 63;
    int h  = lane >> 5;             // 0: even row of pair, 1: odd row
    int iy = lane & 31;
    if (iy >= 28) return;

    float py = fmaf((float)iy, swy, y_lo);
    float y0f = floorf(py);
    float fy = py - y0f;
    int y0 = (int)y0f;
    bool ysafe = (y0 >= 0) && (y0 <= 254);
    int nits = (wave < 2) ? 4 : 3;  /* p = wave, wave+4, wave+8 [, wave+12] */

    float A00[4], A01[4], A10[4], A11[4], FX[4];
    int IX[4];
    #pragma unroll
    for (int it = 0; it < 4; ++it) {
        int p = wave + it * 4;
        int ix = (it < nits) ? (2 * p + h) : h;     /* masked iter re-reads it=0's rows */
        IX[it] = ix;
        float px = fmaf((float)ix, swx, x_lo);
        float x0f = floorf(px);
        FX[it] = px - x0f;
        int x0 = (int)x0f;
        if (ysafe) {
            int xc0 = min(max(x0, 0), 255);
            int xc1 = min(max(x0 + 1, 0), 255);
            f2v v0 = *(const f2v*)(img + xc0 * 256 + y0);
            f2v v1 = *(const f2v*)(img + xc1 * 256 + y0);
            float m0 = ((unsigned)x0 < 256u) ? 1.0f : 0.0f;
            float m1 = ((unsigned)(x0 + 1) < 256u) ? 1.0f : 0.0f;
            A00[it] = v0.x * m0; A01[it] = v0.y * m0;
            A10[it] = v1.x * m1; A11[it] = v1.y * m1;
        } else {
            A00[it] = tap256(img, x0, y0);
            A01[it] = tap256(img, x0, y0 + 1);
            A10[it] = tap256(img, x0 + 1, y0);
            A11[it] = tap256(img, x0 + 1, y0 + 1);
        }
    }
    #pragma unroll
    for (int it = 0; it < 4; ++it) {
        if (it < nits) {
            float fx = FX[it];
            float v = (1.0f - fx) * ((1.0f - fy) * A00[it] + fy * A01[it])
                    +         fx  * ((1.0f - fy) * A10[it] + fy * A11[it]);
            dst[IX[it] * 28 + iy] = v;
        }
    }
}

/* ------------- kernel G: box-shared split-K encoder GEMM (reads materialized crop) ------------- */
__device__ __forceinline__ float dot4f(float4 v, float4 w, float a) {
    return fmaf(v.x, w.x, fmaf(v.y, w.y, fmaf(v.z, w.z, fmaf(v.w, w.w, a))));
}

__global__ __launch_bounds__(512) void enc_gemm_kernel(
        const float* __restrict__ crop,
        const float* __restrict__ w_mu, const float* __restrict__ w_std,
        float* __restrict__ ws_part) {
    int blk = blockIdx.x;
    int g = blk / NCHUNK, chunk = blk - g * NCHUNK;
    int wave = threadIdx.x >> 6, lane = threadIdx.x & 63;
    int base4 = chunk * CH4;
    const float4* cp4 = (const float4*)crop;

    __shared__ float4 crop_lds[8][CH4];   /* 16 KB */
    {
        int t1 = threadIdx.x, t2 = threadIdx.x + 512;
        crop_lds[t1 >> 7][t1 & 127] = cp4[(size_t)(g * 8 + (t1 >> 7)) * FEAT4 + base4 + (t1 & 127)];
        crop_lds[t2 >> 7][t2 & 127] = cp4[(size_t)(g * 8 + (t2 >> 7)) * FEAT4 + base4 + (t2 & 127)];
    }

    int row = wave * 4;
    const float4* wsrc = (row < 16) ? ((const float4*)w_mu + (size_t)row * FEAT4)
                                    : ((const float4*)w_std + (size_t)(row - 16) * FEAT4);
    int i4a = base4 + lane, i4b = i4a + 64;
    float4 wa[4], wb[4];
    #pragma unroll
    for (int r = 0; r < 4; ++r) {
        wa[r] = wsrc[(size_t)r * FEAT4 + i4a];
        wb[r] = wsrc[(size_t)r * FEAT4 + i4b];
    }

    float cur[32];
    #pragma unroll
    for (int j = 0; j < 32; ++j) cur[j] = 0.0f;

    __syncthreads();

    #pragma unroll
    for (int bb = 0; bb < 8; ++bb) {
        float4 ca = crop_lds[bb][lane];
        float4 cb = crop_lds[bb][lane + 64];
        #pragma unroll
        for (int r = 0; r < 4; ++r)
            cur[r * 8 + bb] = dot4f(cb, wb[r], dot4f(ca, wa[r], cur[r * 8 + bb]));
    }

    /* pairing-tree reduce: lane l<32 ends holding full 64-lane sum of cur[l] */
    {   bool bit = (lane & 1) != 0; float nx[16];
        #pragma unroll
        for (int j = 0; j < 16; ++j) {
            float keep = bit ? cur[2*j+1] : cur[2*j];
            float send = bit ? cur[2*j]   : cur[2*j+1];
            nx[j] = keep + __shfl_xor(send, 1);
        }
        #pragma unroll
        for (int j = 0; j < 16; ++j) cur[j] = nx[j];
    }
    {   bool bit = (lane & 2) != 0; float nx[8];
        #pragma unroll
        for (int j = 0; j < 8; ++j) {
            float keep = bit ? cur[2*j+1] : cur[2*j];
            float send = bit ? cur[2*j]   : cur[2*j+1];
            nx[j] = keep + __shfl_xor(send, 2);
        }
        #pragma unroll
        for (int j = 0; j < 8; ++j) cur[j] = nx[j];
    }
    {   bool bit = (lane & 4) != 0; float nx[4];
        #pragma unroll
        for (int j = 0; j < 4; ++j) {
            float keep = bit ? cur[2*j+1] : cur[2*j];
            float send = bit ? cur[2*j]   : cur[2*j+1];
            nx[j] = keep + __shfl_xor(send, 4);
        }
        #pragma unroll
        for (int j = 0; j < 4; ++j) cur[j] = nx[j];
    }
    {   bool bit = (lane & 8) != 0; float nx[2];
        #pragma unroll
        for (int j = 0; j < 2; ++j) {
            float keep = bit ? cur[2*j+1] : cur[2*j];
            float send = bit ? cur[2*j]   : cur[2*j+1];
            nx[j] = keep + __shfl_xor(send, 8);
        }
        cur[0] = nx[0]; cur[1] = nx[1];
    }
    {   bool bit = (lane & 16) != 0;
        float keep = bit ? cur[1] : cur[0];
        float send = bit ? cur[0] : cur[1];
        cur[0] = keep + __shfl_xor(send, 16);
    }
    float tot = cur[0] + __shfl_xor(cur[0], 32);
    if (lane < 32) {
        int kbx = g * 8 + (lane & 7);
        ws_part[((size_t)kbx * NCHUNK + chunk) * 32 + row + (lane >> 3)] = tot;
    }
}

/* ------------- kernel D: finish encoder + decoder GEMV + activations (+ misc maps tail) ------------- */
__global__ __launch_bounds__(256) void dec_enc_kernel(
        const float* __restrict__ ws_part,
        const float* __restrict__ b_mu, const float* __restrict__ b_std,
        const float* __restrict__ w_dec, const float* __restrict__ b_dec,
        const float* __restrict__ logit_mu,
        float* __restrict__ ws_small, float* __restrict__ out) {
    int kb = blockIdx.x;
    int t = threadIdx.x;
    if (kb >= K * B) {
        /* misc maps: blocks 200..231 cover the 8192 logits */
        int i = (kb - K * B) * 256 + t;
        float x = logit_mu[i];
        out[O_LOGIT_MU + i] = x;
        float p = sigmoidf_(x);
        out[O_P_MAP + i] = p;
        out[O_KL_LOGIT + i] = 0.69314718055994531f + p * logf(p + 1e-8f) + (1.0f - p) * logf(1.0f - p + 1e-8f);
        return;
    }
    __shared__ float zsh[DZI], spsh[DZI];
    if (t < 32) {
        float s = 0.0f;
        for (int c = 0; c < NCHUNK; ++c) s += ws_part[((size_t)kb * NCHUNK + c) * 32 + t];
        if (t < DZI) zsh[t] = s + b_mu[t];
        else         spsh[t - DZI] = s + b_std[t - DZI];
    }
    __syncthreads();
    if (t < DZI) {
        float m = zsh[t];
        float sd = softplusf_(spsh[t]);
        out[O_Z_SAMPLE + kb * DZI + t] = m;
        out[O_KL_ZINST + kb * DZI + t] = 0.5f * (sd * sd + m * m - 1.0f) - logf(sd + 1e-8f);
    }
    float z[DZI];
    #pragma unroll
    for (int j = 0; j < DZI; ++j) z[j] = zsh[j];
    for (int o = t; o < OUT_FLAT; o += 256) {
        const float4* wd = (const float4*)(w_dec + o * DZI);
        float4 w0 = wd[0], w1 = wd[1], w2 = wd[2], w3 = wd[3];
        float a = b_dec[o];
        a = fmaf(z[0], w0.x, fmaf(z[1], w0.y, fmaf(z[2], w0.z, fmaf(z[3], w0.w, a))));
        a = fmaf(z[4], w1.x, fmaf(z[5], w1.y, fmaf(z[6], w1.z, fmaf(z[7], w1.w, a))));
        a = fmaf(z[8], w2.x, fmaf(z[9], w2.y, fmaf(z[10], w2.z, fmaf(z[11], w2.w, a))));
        a = fmaf(z[12], w3.x, fmaf(z[13], w3.y, fmaf(z[14], w3.z, fmaf(z[15], w3.w, a))));
        float r = (o < 784) ? sp_fast(a) : sig_fast(a);
        ws_small[(size_t)kb * OUT_FLAT + o] = r;
    }
}

/* ------------- kernel E: uncrop + mask compose, 2 v/thread, wk cached in registers ------------- */
__device__ __forceinline__ void sample2_wi(const float* __restrict__ p0, float sx,
                                           float y_lo, float ih, int v0,
                                           float* __restrict__ w, float* __restrict__ im) {
    const float* p1 = p0 + 784;
    float x0f = floorf(sx); float fx = sx - x0f; int x0 = (int)x0f;
    #pragma unroll
    for (int q = 0; q < 2; ++q) {
        float sy = ((float)(v0 + q) - y_lo) * ih;
        float wv = 0.0f, iv = 0.0f;
        if (sy > -1.0f && sy < 28.0f) {
            float y0f = floorf(sy); float fy = sy - y0f; int y0 = (int)y0f;
            float a00 = tap28(p0, x0, y0),     a01 = tap28(p0, x0, y0 + 1);
            float a10 = tap28(p0, x0 + 1, y0), a11 = tap28(p0, x0 + 1, y0 + 1);
            wv = (1.0f - fx) * ((1.0f - fy) * a00 + fy * a01)
               +         fx  * ((1.0f - fy) * a10 + fy * a11);
            float c00 = tap28(p1, x0, y0),     c01 = tap28(p1, x0, y0 + 1);
            float c10 = tap28(p1, x0 + 1, y0), c11 = tap28(p1, x0 + 1, y0 + 1);
            iv = (1.0f - fx) * ((1.0f - fy) * c00 + fy * c01)
               +         fx  * ((1.0f - fy) * c10 + fy * c11);
        }
        w[q] = wv; im[q] = iv;
    }
}

__global__ __launch_bounds__(256) void uncrop_kernel(const float* __restrict__ ws_small,
                                                     const float* __restrict__ ws_boxes,
                                                     float* __restrict__ out) {
    int blk = blockIdx.x;           // b*128 + ug
    int b = blk >> 7;
    int ug = blk & 127;
    int t = threadIdx.x;
    int u = ug * 2 + (t >> 7);
    int v0 = (t & 127) << 1;

    __shared__ float4 bt[K];   // (x_lo, y_lo, 27/cw, 27/ch)
    if (t < K) {
        float4 bx = ((const float4*)ws_boxes)[t * B + b];
        bt[t] = make_float4(bx.x - 0.5f * bx.z, bx.y - 0.5f * bx.w, 27.0f / bx.z, 27.0f / bx.w);
    }
    __syncthreads();

    float fu = (float)u;
    float sum[2] = {0.0f, 0.0f};
    float wk0[K], wk1[K];          /* per-box weights cached for pass 2 (compile-time indexed) */
    #pragma unroll
    for (int k = 0; k < K; ++k) {
        float4 bb = bt[k];
        float sx = (fu - bb.x) * bb.z;
        float w[2] = {0, 0}, im[2] = {0, 0};
        if (sx > -1.0f && sx < 28.0f) {
            const float* p0 = ws_small + (size_t)(k * B + b) * OUT_FLAT;
            sample2_wi(p0, sx, bb.y, bb.w, v0, w, im);
        }
        sum[0] += w[0]; sum[1] += w[1];
        wk0[k] = w[0]; wk1[k] = w[1];
        size_t base = (((size_t)(k * B + b) * 256 + u) * 256 + v0);
        *(float2*)(out + O_BIG_IMG + base) = make_float2(im[0], im[1]);
        *(float2*)(out + O_BIG_MASK_NON + base) = make_float2(tanh_fast(w[0]), tanh_fast(w[1]));
    }
    float sc[2];
    sc[0] = tanh_fast(sum[0]) / fmaxf(sum[0], 1e-6f);
    sc[1] = tanh_fast(sum[1]) / fmaxf(sum[1], 1e-6f);
    #pragma unroll
    for (int k = 0; k < K; ++k) {
        size_t base = (((size_t)(k * B + b) * 256 + u) * 256 + v0);
        *(float2*)(out + O_BIG_MASK + base) = make_float2(wk0[k] * sc[0], wk1[k] * sc[1]);
    }
}

extern "C" void kernel_launch(void* const* d_in, const int* in_sizes, int n_in,
                              void* d_out, int out_size, void* d_ws, size_t ws_size,
                              hipStream_t stream) {
    const float* features = (const float*)d_in[1];
    const float* zwhere_mu = (const float*)d_in[2];
    const float* zwhere_std = (const float*)d_in[3];
    const float* logit_mu = (const float*)d_in[4];
    const float* w_zwhere = (const float*)d_in[5];
    const float* b_zwhere = (const float*)d_in[6];
    const float* w_enc_mu = (const float*)d_in[7];
    const float* b_enc_mu = (const float*)d_in[8];
    const float* w_enc_std = (const float*)d_in[9];
    const float* b_enc_std = (const float*)d_in[10];
    const float* w_dec = (const float*)d_in[11];
    const float* b_dec = (const float*)d_in[12];
    float* out = (float*)d_out;

    float* ws_boxes = (float*)d_ws;                     // 800 floats
    float* ws_part  = ws_boxes + 200 * 4;               // 200*49*32 = 313600 floats
    float* ws_small = ws_part + 200 * NCHUNK * 32;      // 313600 floats
    /* crop scratch (20 MB) lives in out's big_img region; uncrop overwrites it last */
    float* ws_crop  = out + O_BIG_IMG;

    hipLaunchKernelGGL(topk_kernel, dim3(B), dim3(64), 0, stream,
                       logit_mu, zwhere_mu, zwhere_std, w_zwhere, b_zwhere, out, ws_boxes);
    hipLaunchKernelGGL(crop_writer_kernel, dim3(FCH, 200), dim3(256), 0, stream,
                       features, ws_boxes, ws_crop);
    hipLaunchKernelGGL(enc_gemm_kernel, dim3(25 * NCHUNK), dim3(512), 0, stream,
                       ws_crop, w_enc_mu, w_enc_std, ws_part);
    hipLaunchKernelGGL(dec_enc_kernel, dim3(K * B + 32), dim3(256), 0, stream,
                       ws_part, b_enc_mu, b_enc_std, w_dec, b_dec, logit_mu, ws_small, out);
    hipLaunchKernelGGL(uncrop_kernel, dim3(B * 128), dim3(256), 0, stream,
                       ws_small, ws_boxes, out);
}

// Round 17
// 104.252 us; speedup vs baseline: 1.0218x; 1.0218x over previous
//
#include <hip/hip_runtime.h>
#include <math.h>

#define B 8
#define FCH 32
#define WI 256
#define HI 256
#define NW 32
#define NH 32
#define NBOX 1024
#define K 25
#define S 28
#define DZI 16
#define FEAT_FLAT (FCH*S*S)   /* 25088 */
#define FEAT4 (FEAT_FLAT/4)   /* 6272 */
#define OUT_FLAT (2*S*S)      /* 1568 */
#define SMIN 24.0f
#define SMAX 96.0f
#define BIG_SZ (K*B*WI*HI)    /* 13,107,200 */

#define NCHUNK 49
#define CH4 128               /* float4 groups per chunk */

/* output offsets (floats), in reference return order */
#define O_LOGIT_MU    0
#define O_LOGIT_FEW   8192
#define O_BIG_MASK    8392
#define O_BIG_MASK_NON (O_BIG_MASK + BIG_SZ)
#define O_BIG_IMG     (O_BIG_MASK_NON + BIG_SZ)
#define O_P_MAP       (O_BIG_IMG + BIG_SZ)
#define O_C_FEW       (O_P_MAP + 8192)
#define O_BX          (O_C_FEW + 200)
#define O_BY          (O_BX + 200)
#define O_BW          (O_BY + 200)
#define O_BH          (O_BW + 200)
#define O_Z_SAMPLE    (O_BH + 200)
#define O_KL_LOGIT    (O_Z_SAMPLE + 3200)
#define O_KL_ZWHERE   (O_KL_LOGIT + 8192)
#define O_KL_ZINST    (O_KL_ZWHERE + 800)

__device__ __forceinline__ float sigmoidf_(float x) { return 1.0f / (1.0f + expf(-x)); }
__device__ __forceinline__ float softplusf_(float x) { return fmaxf(x, 0.0f) + log1pf(expf(-fabsf(x))); }
__device__ __forceinline__ float sig_fast(float x) { return 1.0f / (1.0f + __expf(-x)); }
__device__ __forceinline__ float sp_fast(float x)  { return fmaxf(x, 0.0f) + __logf(1.0f + __expf(-fabsf(x))); }
__device__ __forceinline__ float tanh_fast(float x) { /* x >= 0 */
    float e = __expf(-2.0f * x);
    return (1.0f - e) / (1.0f + e);
}

__device__ __forceinline__ float tap256(const float* img, int x, int y) {
    bool in = ((unsigned)x < 256u) && ((unsigned)y < 256u);
    int xc = min(max(x, 0), 255), yc = min(max(y, 0), 255);
    float v = img[xc * 256 + yc];
    return in ? v : 0.0f;
}

__device__ __forceinline__ float tap28(const float* img, int x, int y) {
    bool in = ((unsigned)x < 28u) && ((unsigned)y < 28u);
    int xc = min(max(x, 0), 27), yc = min(max(y, 0), 27);
    float v = img[xc * 28 + yc];
    return in ? v : 0.0f;
}

/* ------------- kernel T: per-batch top-k + box params + kl_zwhere ------------- */
__global__ void topk_kernel(const float* __restrict__ logit_mu,
                            const float* __restrict__ zmu, const float* __restrict__ zstd,
                            const float* __restrict__ w_zw, const float* __restrict__ b_zw,
                            float* __restrict__ out, float* __restrict__ ws_boxes) {
    int b = blockIdx.x;
    int lane = threadIdx.x;          // 64 lanes, one wave
    const float* lg = logit_mu + b * NBOX;
    float vals[16];
    #pragma unroll
    for (int m = 0; m < 16; ++m) vals[m] = lg[m * 64 + lane];

    unsigned taken = 0;
    int sel_idx = 0;
    for (int ks = 0; ks < K; ++ks) {
        float bv = -INFINITY; int bi = 0x7fffffff;
        #pragma unroll
        for (int m = 0; m < 16; ++m) {
            if (!(taken & (1u << m))) {
                float v = vals[m]; int idx = m * 64 + lane;
                if (v > bv || (v == bv && idx < bi)) { bv = v; bi = idx; }
            }
        }
        #pragma unroll
        for (int sh = 32; sh >= 1; sh >>= 1) {
            float ov = __shfl_xor(bv, sh);
            int   oi = __shfl_xor(bi, sh);
            if (ov > bv || (ov == bv && oi < bi)) { bv = ov; bi = oi; }
        }
        if ((bi & 63) == lane) taken |= (1u << (bi >> 6));
        if (lane == ks) sel_idx = bi;
        if (lane == 0) {
            out[O_LOGIT_FEW + ks * B + b] = bv;
            out[O_C_FEW + ks * B + b] = sigmoidf_(bv);
        }
    }

    if (lane < K) {
        int idx = sel_idx;
        int w = idx >> 5, h = idx & 31;
        float mu_c[4];
        #pragma unroll
        for (int c = 0; c < 4; ++c) mu_c[c] = zmu[((b * 4 + c) * NW + w) * NH + h];
        float t[4];
        #pragma unroll
        for (int o = 0; o < 4; ++o) {
            float a = b_zw[o];
            #pragma unroll
            for (int c = 0; c < 4; ++c) a = fmaf(mu_c[c], w_zw[o * 4 + c], a);
            t[o] = sigmoidf_(a);
        }
        float bx = (float)WI * ((float)w + t[0]) / (float)NW;
        float by = (float)HI * ((float)h + t[1]) / (float)NH;
        float bw = SMIN + (SMAX - SMIN) * t[2];
        float bh = SMIN + (SMAX - SMIN) * t[3];
        int kb = lane * B + b;
        out[O_BX + kb] = bx;
        out[O_BY + kb] = by;
        out[O_BW + kb] = bw;
        out[O_BH + kb] = bh;
        ((float4*)ws_boxes)[kb] = make_float4(bx, by, bw, bh);
        #pragma unroll
        for (int c = 0; c < 4; ++c) {
            float m = mu_c[c];
            float sd = zstd[((b * 4 + c) * NW + w) * NH + h];
            out[O_KL_ZWHERE + kb * 4 + c] = 0.5f * (sd * sd + m * m - 1.0f) - logf(sd);
        }
    }
}

/* ------------- kernel W: row-pair crop writer, fully unrolled (16 taps in flight) ------------- */
__global__ __launch_bounds__(256) void crop_writer_kernel(
        const float* __restrict__ features, const float* __restrict__ ws_boxes,
        float* __restrict__ crop) {
    int c  = blockIdx.x;            // channel
    int kb = blockIdx.y;            // box (k*8+b)
    int b  = kb & 7;
    float4 box = ((const float4*)ws_boxes)[kb];
    float x_lo = box.x - 0.5f * box.z, y_lo = box.y - 0.5f * box.w;
    float swx = box.z * (1.0f / 27.0f), swy = box.w * (1.0f / 27.0f);
    const float* img = features + ((size_t)b * FCH + c) * (WI * HI);
    float* dst = crop + (size_t)kb * FEAT_FLAT + c * 784;

    int wave = threadIdx.x >> 6, lane = threadIdx.x & 63;
    int h  = lane >> 5;             // 0: even row of pair, 1: odd row
    int iy = lane & 31;
    if (iy >= 28) return;

    float py = fmaf((float)iy, swy, y_lo);
    float y0f = floorf(py);
    float fy = py - y0f;
    int y0 = (int)y0f;
    int nits = (wave < 2) ? 4 : 3;  /* p = wave, wave+4, wave+8 [, wave+12] */

    float A00[4], A01[4], A10[4], A11[4], FX[4];
    int IX[4];
    #pragma unroll
    for (int it = 0; it < 4; ++it) {
        int p = wave + it * 4;
        int ix = (it < nits) ? (2 * p + h) : h;     /* masked iter re-reads it=0's rows */
        IX[it] = ix;
        float px = fmaf((float)ix, swx, x_lo);
        float x0f = floorf(px);
        FX[it] = px - x0f;
        int x0 = (int)x0f;
        A00[it] = tap256(img, x0, y0);
        A01[it] = tap256(img, x0, y0 + 1);
        A10[it] = tap256(img, x0 + 1, y0);
        A11[it] = tap256(img, x0 + 1, y0 + 1);
    }
    #pragma unroll
    for (int it = 0; it < 4; ++it) {
        if (it < nits) {
            float fx = FX[it];
            float v = (1.0f - fx) * ((1.0f - fy) * A00[it] + fy * A01[it])
                    +         fx  * ((1.0f - fy) * A10[it] + fy * A11[it]);
            dst[IX[it] * 28 + iy] = v;
        }
    }
}

/* ------------- kernel G: box-shared split-K encoder GEMM (reads materialized crop) ------------- */
__device__ __forceinline__ float dot4f(float4 v, float4 w, float a) {
    return fmaf(v.x, w.x, fmaf(v.y, w.y, fmaf(v.z, w.z, fmaf(v.w, w.w, a))));
}

__global__ __launch_bounds__(512) void enc_gemm_kernel(
        const float* __restrict__ crop,
        const float* __restrict__ w_mu, const float* __restrict__ w_std,
        float* __restrict__ ws_part) {
    int blk = blockIdx.x;
    int g = blk / NCHUNK, chunk = blk - g * NCHUNK;
    int wave = threadIdx.x >> 6, lane = threadIdx.x & 63;
    int base4 = chunk * CH4;
    const float4* cp4 = (const float4*)crop;

    __shared__ float4 crop_lds[8][CH4];   /* 16 KB */
    {
        int t1 = threadIdx.x, t2 = threadIdx.x + 512;
        crop_lds[t1 >> 7][t1 & 127] = cp4[(size_t)(g * 8 + (t1 >> 7)) * FEAT4 + base4 + (t1 & 127)];
        crop_lds[t2 >> 7][t2 & 127] = cp4[(size_t)(g * 8 + (t2 >> 7)) * FEAT4 + base4 + (t2 & 127)];
    }

    int row = wave * 4;
    const float4* wsrc = (row < 16) ? ((const float4*)w_mu + (size_t)row * FEAT4)
                                    : ((const float4*)w_std + (size_t)(row - 16) * FEAT4);
    int i4a = base4 + lane, i4b = i4a + 64;
    float4 wa[4], wb[4];
    #pragma unroll
    for (int r = 0; r < 4; ++r) {
        wa[r] = wsrc[(size_t)r * FEAT4 + i4a];
        wb[r] = wsrc[(size_t)r * FEAT4 + i4b];
    }

    float cur[32];
    #pragma unroll
    for (int j = 0; j < 32; ++j) cur[j] = 0.0f;

    __syncthreads();

    #pragma unroll
    for (int bb = 0; bb < 8; ++bb) {
        float4 ca = crop_lds[bb][lane];
        float4 cb = crop_lds[bb][lane + 64];
        #pragma unroll
        for (int r = 0; r < 4; ++r)
            cur[r * 8 + bb] = dot4f(cb, wb[r], dot4f(ca, wa[r], cur[r * 8 + bb]));
    }

    /* pairing-tree reduce: lane l<32 ends holding full 64-lane sum of cur[l] */
    {   bool bit = (lane & 1) != 0; float nx[16];
        #pragma unroll
        for (int j = 0; j < 16; ++j) {
            float keep = bit ? cur[2*j+1] : cur[2*j];
            float send = bit ? cur[2*j]   : cur[2*j+1];
            nx[j] = keep + __shfl_xor(send, 1);
        }
        #pragma unroll
        for (int j = 0; j < 16; ++j) cur[j] = nx[j];
    }
    {   bool bit = (lane & 2) != 0; float nx[8];
        #pragma unroll
        for (int j = 0; j < 8; ++j) {
            float keep = bit ? cur[2*j+1] : cur[2*j];
            float send = bit ? cur[2*j]   : cur[2*j+1];
            nx[j] = keep + __shfl_xor(send, 2);
        }
        #pragma unroll
        for (int j = 0; j < 8; ++j) cur[j] = nx[j];
    }
    {   bool bit = (lane & 4) != 0; float nx[4];
        #pragma unroll
        for (int j = 0; j < 4; ++j) {
            float keep = bit ? cur[2*j+1] : cur[2*j];
            float send = bit ? cur[2*j]   : cur[2*j+1];
            nx[j] = keep + __shfl_xor(send, 4);
        }
        #pragma unroll
        for (int j = 0; j < 4; ++j) cur[j] = nx[j];
    }
    {   bool bit = (lane & 8) != 0; float nx[2];
        #pragma unroll
        for (int j = 0; j < 2; ++j) {
            float keep = bit ? cur[2*j+1] : cur[2*j];
            float send = bit ? cur[2*j]   : cur[2*j+1];
            nx[j] = keep + __shfl_xor(send, 8);
        }
        cur[0] = nx[0]; cur[1] = nx[1];
    }
    {   bool bit = (lane & 16) != 0;
        float keep = bit ? cur[1] : cur[0];
        float send = bit ? cur[0] : cur[1];
        cur[0] = keep + __shfl_xor(send, 16);
    }
    float tot = cur[0] + __shfl_xor(cur[0], 32);
    if (lane < 32) {
        int kbx = g * 8 + (lane & 7);
        ws_part[((size_t)kbx * NCHUNK + chunk) * 32 + row + (lane >> 3)] = tot;
    }
}

/* ------------- kernel D: finish encoder + decoder GEMV + activations (+ misc maps tail) ------------- */
__global__ __launch_bounds__(256) void dec_enc_kernel(
        const float* __restrict__ ws_part,
        const float* __restrict__ b_mu, const float* __restrict__ b_std,
        const float* __restrict__ w_dec, const float* __restrict__ b_dec,
        const float* __restrict__ logit_mu,
        float* __restrict__ ws_small, float* __restrict__ out) {
    int kb = blockIdx.x;
    int t = threadIdx.x;
    if (kb >= K * B) {
        /* misc maps: blocks 200..231 cover the 8192 logits */
        int i = (kb - K * B) * 256 + t;
        float x = logit_mu[i];
        out[O_LOGIT_MU + i] = x;
        float p = sigmoidf_(x);
        out[O_P_MAP + i] = p;
        out[O_KL_LOGIT + i] = 0.69314718055994531f + p * logf(p + 1e-8f) + (1.0f - p) * logf(1.0f - p + 1e-8f);
        return;
    }
    __shared__ float zsh[DZI], spsh[DZI];
    if (t < 32) {
        float s = 0.0f;
        for (int c = 0; c < NCHUNK; ++c) s += ws_part[((size_t)kb * NCHUNK + c) * 32 + t];
        if (t < DZI) zsh[t] = s + b_mu[t];
        else         spsh[t - DZI] = s + b_std[t - DZI];
    }
    __syncthreads();
    if (t < DZI) {
        float m = zsh[t];
        float sd = softplusf_(spsh[t]);
        out[O_Z_SAMPLE + kb * DZI + t] = m;
        out[O_KL_ZINST + kb * DZI + t] = 0.5f * (sd * sd + m * m - 1.0f) - logf(sd + 1e-8f);
    }
    float z[DZI];
    #pragma unroll
    for (int j = 0; j < DZI; ++j) z[j] = zsh[j];
    for (int o = t; o < OUT_FLAT; o += 256) {
        const float4* wd = (const float4*)(w_dec + o * DZI);
        float4 w0 = wd[0], w1 = wd[1], w2 = wd[2], w3 = wd[3];
        float a = b_dec[o];
        a = fmaf(z[0], w0.x, fmaf(z[1], w0.y, fmaf(z[2], w0.z, fmaf(z[3], w0.w, a))));
        a = fmaf(z[4], w1.x, fmaf(z[5], w1.y, fmaf(z[6], w1.z, fmaf(z[7], w1.w, a))));
        a = fmaf(z[8], w2.x, fmaf(z[9], w2.y, fmaf(z[10], w2.z, fmaf(z[11], w2.w, a))));
        a = fmaf(z[12], w3.x, fmaf(z[13], w3.y, fmaf(z[14], w3.z, fmaf(z[15], w3.w, a))));
        float r = (o < 784) ? sp_fast(a) : sig_fast(a);
        ws_small[(size_t)kb * OUT_FLAT + o] = r;
    }
}

/* ------------- kernel E: uncrop + mask compose, 2 v/thread, wk cached in registers ------------- */
__device__ __forceinline__ void sample2_wi(const float* __restrict__ p0, float sx,
                                           float y_lo, float ih, int v0,
                                           float* __restrict__ w, float* __restrict__ im) {
    const float* p1 = p0 + 784;
    float x0f = floorf(sx); float fx = sx - x0f; int x0 = (int)x0f;
    #pragma unroll
    for (int q = 0; q < 2; ++q) {
        float sy = ((float)(v0 + q) - y_lo) * ih;
        float wv = 0.0f, iv = 0.0f;
        if (sy > -1.0f && sy < 28.0f) {
            float y0f = floorf(sy); float fy = sy - y0f; int y0 = (int)y0f;
            float a00 = tap28(p0, x0, y0),     a01 = tap28(p0, x0, y0 + 1);
            float a10 = tap28(p0, x0 + 1, y0), a11 = tap28(p0, x0 + 1, y0 + 1);
            wv = (1.0f - fx) * ((1.0f - fy) * a00 + fy * a01)
               +         fx  * ((1.0f - fy) * a10 + fy * a11);
            float c00 = tap28(p1, x0, y0),     c01 = tap28(p1, x0, y0 + 1);
            float c10 = tap28(p1, x0 + 1, y0), c11 = tap28(p1, x0 + 1, y0 + 1);
            iv = (1.0f - fx) * ((1.0f - fy) * c00 + fy * c01)
               +         fx  * ((1.0f - fy) * c10 + fy * c11);
        }
        w[q] = wv; im[q] = iv;
    }
}

__global__ __launch_bounds__(256) void uncrop_kernel(const float* __restrict__ ws_small,
                                                     const float* __restrict__ ws_boxes,
                                                     float* __restrict__ out) {
    int blk = blockIdx.x;           // b*128 + ug
    int b = blk >> 7;
    int ug = blk & 127;
    int t = threadIdx.x;
    int u = ug * 2 + (t >> 7);
    int v0 = (t & 127) << 1;

    __shared__ float4 bt[K];   // (x_lo, y_lo, 27/cw, 27/ch)
    if (t < K) {
        float4 bx = ((const float4*)ws_boxes)[t * B + b];
        bt[t] = make_float4(bx.x - 0.5f * bx.z, bx.y - 0.5f * bx.w, 27.0f / bx.z, 27.0f / bx.w);
    }
    __syncthreads();

    float fu = (float)u;
    float sum[2] = {0.0f, 0.0f};
    float wk0[K], wk1[K];          /* per-box weights cached for pass 2 (compile-time indexed) */
    #pragma unroll
    for (int k = 0; k < K; ++k) {
        float4 bb = bt[k];
        float sx = (fu - bb.x) * bb.z;
        float w[2] = {0, 0}, im[2] = {0, 0};
        if (sx > -1.0f && sx < 28.0f) {
            const float* p0 = ws_small + (size_t)(k * B + b) * OUT_FLAT;
            sample2_wi(p0, sx, bb.y, bb.w, v0, w, im);
        }
        sum[0] += w[0]; sum[1] += w[1];
        wk0[k] = w[0]; wk1[k] = w[1];
        size_t base = (((size_t)(k * B + b) * 256 + u) * 256 + v0);
        *(float2*)(out + O_BIG_IMG + base) = make_float2(im[0], im[1]);
        *(float2*)(out + O_BIG_MASK_NON + base) = make_float2(tanh_fast(w[0]), tanh_fast(w[1]));
    }
    float sc[2];
    sc[0] = tanh_fast(sum[0]) / fmaxf(sum[0], 1e-6f);
    sc[1] = tanh_fast(sum[1]) / fmaxf(sum[1], 1e-6f);
    #pragma unroll
    for (int k = 0; k < K; ++k) {
        size_t base = (((size_t)(k * B + b) * 256 + u) * 256 + v0);
        *(float2*)(out + O_BIG_MASK + base) = make_float2(wk0[k] * sc[0], wk1[k] * sc[1]);
    }
}

extern "C" void kernel_launch(void* const* d_in, const int* in_sizes, int n_in,
                              void* d_out, int out_size, void* d_ws, size_t ws_size,
                              hipStream_t stream) {
    const float* features = (const float*)d_in[1];
    const float* zwhere_mu = (const float*)d_in[2];
    const float* zwhere_std = (const float*)d_in[3];
    const float* logit_mu = (const float*)d_in[4];
    const float* w_zwhere = (const float*)d_in[5];
    const float* b_zwhere = (const float*)d_in[6];
    const float* w_enc_mu = (const float*)d_in[7];
    const float* b_enc_mu = (const float*)d_in[8];
    const float* w_enc_std = (const float*)d_in[9];
    const float* b_enc_std = (const float*)d_in[10];
    const float* w_dec = (const float*)d_in[11];
    const float* b_dec = (const float*)d_in[12];
    float* out = (float*)d_out;

    float* ws_boxes = (float*)d_ws;                     // 800 floats
    float* ws_part  = ws_boxes + 200 * 4;               // 200*49*32 = 313600 floats
    float* ws_small = ws_part + 200 * NCHUNK * 32;      // 313600 floats
    /* crop scratch (20 MB) lives in out's big_img region; uncrop overwrites it last */
    float* ws_crop  = out + O_BIG_IMG;

    hipLaunchKernelGGL(topk_kernel, dim3(B), dim3(64), 0, stream,
                       logit_mu, zwhere_mu, zwhere_std, w_zwhere, b_zwhere, out, ws_boxes);
    hipLaunchKernelGGL(crop_writer_kernel, dim3(FCH, 200), dim3(256), 0, stream,
                       features, ws_boxes, ws_crop);
    hipLaunchKernelGGL(enc_gemm_kernel, dim3(25 * NCHUNK), dim3(512), 0, stream,
                       ws_crop, w_enc_mu, w_enc_std, ws_part);
    hipLaunchKernelGGL(dec_enc_kernel, dim3(K * B + 32), dim3(256), 0, stream,
                       ws_part, b_enc_mu, b_enc_std, w_dec, b_dec, logit_mu, ws_small, out);
    hipLaunchKernelGGL(uncrop_kernel, dim3(B * 128), dim3(256), 0, stream,
                       ws_small, ws_boxes, out);
}